// Round 19
// baseline (52.483 us; speedup 1.0000x reference)
//
#include <hip/hip_runtime.h>
#include <math.h>

#define NXg 512
#define NYg 512
#define NSEG (NXg * NYg)   // 262144 = 2^18
#define CCH 64
#define CAP 16             // total capacity per pillar (first + 15 ext)
#define ECAP 15            // ext slots per pillar
#define SEGP 4096          // pillars per segment
#define CHG 4              // channels per block
#define BN_EPS 1e-3f

// grid constants (f32, as in the reference arrays)
#define PCMINX (-51.2f)
#define PCMINY (-51.2f)
#define PCMINZ (-3.0f)
#define PCMAXX (51.2f)
#define PCMAXY (51.2f)
#define PCMAXZ (3.0f)
#define VOXX (0.2f)
#define VOXY (0.2f)
#define VOXZ (6.0f)

// f32-exact reciprocals (XLA fast-math computes (p-min)*(1/voxel) in f32).
#define RECIPX 5.0f
#define RECIPY 5.0f
#define RECIPZ (__uint_as_float(0x3E2AAAABu))   // (float)(1/6.0f)

__device__ __forceinline__ int calc_pid(float x, float y, float z) {
    bool in_range = (x >= PCMINX) && (x < PCMAXX) &&
                    (y >= PCMINY) && (y < PCMAXY) &&
                    (z >= PCMINZ) && (z < PCMAXZ);
    if (!in_range) return -1;
    int cx = (int)floorf((x - PCMINX) * RECIPX);
    int cy = (int)floorf((y - PCMINY) * RECIPY);
    int p = cy * NXg + cx;
    return (p >= 0 && p < NSEG) ? p : -1;
}

// K0: zero cnt + build folded per-channel constant table (12 floats/channel):
// [Ac,Bc,Cc,s8 | s3,s4,s5,s6 | s7,shift,0,0]
__global__ void k0_init(unsigned* __restrict__ cnt, float* __restrict__ cTab,
                        const float* __restrict__ W,
                        const float* __restrict__ gamma,
                        const float* __restrict__ beta,
                        const float* __restrict__ rmean,
                        const float* __restrict__ rvar, int BN) {
    int i = blockIdx.x * blockDim.x + threadIdx.x;
    if (i < BN) cnt[i] = 0u;
    if (blockIdx.x == 0 && threadIdx.x < CCH) {
        int c = threadIdx.x;
        float w0 = W[0 * CCH + c], w1 = W[1 * CCH + c], w2 = W[2 * CCH + c];
        float w3 = W[3 * CCH + c], w4 = W[4 * CCH + c], w5 = W[5 * CCH + c];
        float w6 = W[6 * CCH + c], w7 = W[7 * CCH + c], w8 = W[8 * CCH + c];
        float sc = gamma[c] * (1.0f / sqrtf(rvar[c] + BN_EPS));
        float shift = beta[c] - rmean[c] * sc;
        cTab[c * 12 + 0] = (w0 + w3 + w6) * sc;   // Ac
        cTab[c * 12 + 1] = (w1 + w4 + w7) * sc;   // Bc
        cTab[c * 12 + 2] = (w2 + w5) * sc;        // Cc
        cTab[c * 12 + 3] = w8 * sc;               // s8
        cTab[c * 12 + 4] = w3 * sc;               // s3
        cTab[c * 12 + 5] = w4 * sc;               // s4
        cTab[c * 12 + 6] = w5 * sc;               // s5
        cTab[c * 12 + 7] = w6 * sc;               // s6
        cTab[c * 12 + 8] = w7 * sc;               // s7
        cTab[c * 12 + 9] = shift;                 // shift
        cTab[c * 12 + 10] = 0.0f;
        cTab[c * 12 + 11] = 0.0f;
    }
}

// K1: bin points; w component carries the precomputed z-center offset.
__global__ void k1_bin(const float* __restrict__ pts, unsigned* __restrict__ cnt,
                       float4* __restrict__ first, float4* __restrict__ ext,
                       int B, int N) {
    int i = blockIdx.x * blockDim.x + threadIdx.x;
    if (i >= B * N) return;
    const float* p = pts + (size_t)i * 3;
    float x = p[0], y = p[1], z = p[2];
    int pd = calc_pid(x, y, z);
    if (pd < 0) return;
    int b = i / N;
    int g = b * NSEG + pd;
    unsigned slot = atomicAdd(&cnt[g], 1u);
    float cz = floorf((z - PCMINZ) * RECIPZ);
    float ctz = (cz + 0.5f) * VOXZ + PCMINZ;
    float4 e; e.x = x; e.y = y; e.z = z; e.w = z - ctz;   // zc precomputed
    if (slot == 0) first[g] = e;
    else if (slot < CAP) ext[(size_t)g * ECAP + (slot - 1)] = e;
}

// K4: block = (batch, 4096-pillar segment, 4-channel group). Each block
// writes 4 CONTIGUOUS 16KB canvas runs (float4 stores) — 64x longer streams
// than the old 256B-per-row pattern. No LDS, no barriers. Per-pillar data
// (cnt+first, 80KB/segment) is shared by the 16 chgroup-blocks of a segment:
// the blockIdx mapping clusters them consecutively on one XCD for L2 reuse
// (L3 catches the reuse regardless: 10.4MB total).
__global__ void __launch_bounds__(256) k4_compute(
    const unsigned* __restrict__ cnt, const float4* __restrict__ first,
    const float4* __restrict__ ext, const float* __restrict__ cTab,
    float* __restrict__ out) {
    int i = (int)blockIdx.x;
    int xcd = i & 7;
    int j = i >> 3;
    int chg = j & 15;            // 16 channel groups (CCH/CHG)
    int ow  = j >> 4;
    int outer = ow * 8 + xcd;    // 0..127 = (b, seg); bijective, XCD-clustered
    int b   = outer >> 6;
    int seg = outer & 63;
    int c0  = chg * CHG;
    int t = threadIdx.x;

    // per-channel folded constants (uniform per block -> scalar loads)
    float AC[CHG], BC[CHG], CC0[CHG], S8[CHG], S3[CHG], S4[CHG], S5[CHG],
          S6[CHG], S7[CHG], SH[CHG];
#pragma unroll
    for (int cc = 0; cc < CHG; ++cc) {
        const float* q = cTab + (size_t)(c0 + cc) * 12;
        AC[cc] = q[0]; BC[cc] = q[1]; CC0[cc] = q[2]; S8[cc] = q[3];
        S3[cc] = q[4]; S4[cc] = q[5]; S5[cc] = q[6]; S6[cc] = q[7];
        S7[cc] = q[8]; SH[cc] = q[9];
    }

    int pbase = seg * SEGP;                 // pillar index within batch
    int gpb = b * NSEG + pbase;             // global pillar base
    size_t orow0 = ((size_t)(b * CCH + c0)) * NSEG + pbase;

#pragma unroll
    for (int jj = 0; jj < 4; ++jj) {
        int p0 = jj * 1024 + t * 4;         // 4 consecutive pillars / thread
        uint4 kv = *reinterpret_cast<const uint4*>(cnt + gpb + p0);
        unsigned ka[4] = {kv.x, kv.y, kv.z, kv.w};
        float4 fa[4];
        fa[0] = first[gpb + p0 + 0];
        fa[1] = first[gpb + p0 + 1];
        fa[2] = first[gpb + p0 + 2];
        fa[3] = first[gpb + p0 + 3];

        float accv[CHG][4];
#pragma unroll
        for (int cc = 0; cc < CHG; ++cc)
#pragma unroll
            for (int pi = 0; pi < 4; ++pi) accv[cc][pi] = 0.0f;

#pragma unroll
        for (int pi = 0; pi < 4; ++pi) {
            int k = (ka[pi] < CAP) ? (int)ka[pi] : CAP;
            if (k == 0) continue;
            float x = fa[pi].x, y = fa[pi].y, z = fa[pi].z, zc = fa[pi].w;
            int p = pbase + p0 + pi;        // pillar id within batch
            float ctx = ((float)(p & (NXg - 1)) + 0.5f) * VOXX + PCMINX;
            float cty = ((float)(p >> 9) + 0.5f) * VOXY + PCMINY;
            const float4* exp_ = ext + (size_t)(gpb + p0 + pi) * ECAP;
            float mx, my, mz, rk;
            if (k == 1) { mx = x; my = y; mz = z; rk = 1.0f; }
            else {                           // ~4% of occupied pillars
                float sx = x, sy = y, sz = z;
                for (int u = 1; u < k; ++u) {
                    float4 e = exp_[u - 1];
                    sx += e.x; sy += e.y; sz += e.z;
                }
                rk = 1.0f / (float)k;
                mx = sx * rk; my = sy * rk; mz = sz * rk;
            }
            float D[CHG], a[CHG];
#pragma unroll
            for (int cc = 0; cc < CHG; ++cc) {
                float Dv = SH[cc];
                Dv = fmaf(-mx, S3[cc], Dv);
                Dv = fmaf(-my, S4[cc], Dv);
                Dv = fmaf(-mz, S5[cc], Dv);
                Dv = fmaf(-ctx, S6[cc], Dv);
                Dv = fmaf(-cty, S7[cc], Dv);
                D[cc] = Dv;
                float h = fmaf(x, AC[cc], fmaf(y, BC[cc],
                              fmaf(z, CC0[cc], fmaf(zc, S8[cc], Dv))));
                a[cc] = fmaxf(h, 0.0f);
            }
            if (k >= 2) {
                for (int u = 1; u < k; ++u) {
                    float4 e = exp_[u - 1];   // L1-hot (read in mean walk)
#pragma unroll
                    for (int cc = 0; cc < CHG; ++cc) {
                        float h = fmaf(e.x, AC[cc], fmaf(e.y, BC[cc],
                                      fmaf(e.z, CC0[cc], fmaf(e.w, S8[cc], D[cc]))));
                        a[cc] += fmaxf(h, 0.0f);
                    }
                }
            }
#pragma unroll
            for (int cc = 0; cc < CHG; ++cc) accv[cc][pi] = a[cc] * rk;
        }

        // 4 float4 stores -> 4 channel rows; per (jj,cc): 256 threads x 16B
        // = 4KB contiguous; per block-row across jj: 16KB contiguous.
#pragma unroll
        for (int cc = 0; cc < CHG; ++cc) {
            float4 v;
            v.x = accv[cc][0]; v.y = accv[cc][1];
            v.z = accv[cc][2]; v.w = accv[cc][3];
            *reinterpret_cast<float4*>(out + orow0 + (size_t)cc * NSEG + p0) = v;
        }
    }
}

extern "C" void kernel_launch(void* const* d_in, const int* in_sizes, int n_in,
                              void* d_out, int out_size, void* d_ws, size_t ws_size,
                              hipStream_t stream) {
    const float* points = (const float*)d_in[0];
    const float* W      = (const float*)d_in[1];
    const float* gamma  = (const float*)d_in[2];
    const float* beta   = (const float*)d_in[3];
    const float* rmean  = (const float*)d_in[4];
    const float* rvar   = (const float*)d_in[5];
    float* out = (float*)d_out;

    int B = out_size / (CCH * NSEG);          // 2
    int N = in_sizes[0] / (3 * B);            // 100000
    int BN = B * NSEG;                        // 524288
    int total_pts = B * N;

    // workspace: cnt [BN] u32 (2 MB) + cTab [64*12 -> 1024 f32 pad] (4 KB)
    //          + first [BN] float4 (8.4 MB) + ext [BN*15] float4 (126 MB)
    unsigned* cnt = (unsigned*)d_ws;
    float* cTab   = (float*)(cnt + BN);
    float4* first = (float4*)(cTab + 1024);
    float4* ext   = first + BN;

    int blk = 256;
    k0_init<<<(BN + blk - 1) / blk, blk, 0, stream>>>(cnt, cTab, W, gamma,
                                                      beta, rmean, rvar, BN);
    int grd_pts = (total_pts + blk - 1) / blk;
    k1_bin<<<grd_pts, blk, 0, stream>>>(points, cnt, first, ext, B, N);
    int nblocks = (BN / SEGP) * (CCH / CHG);  // 128 * 16 = 2048
    k4_compute<<<nblocks, blk, 0, stream>>>(cnt, first, ext, cTab, out);
}